// Round 6
// baseline (1868.404 us; speedup 1.0000x reference)
//
#include <hip/hip_runtime.h>

// ---------------------------------------------------------------------------
// NASNet controller, fully fused: ONE persistent kernel (512 blocks x 256),
// plain launch + hand-rolled sense-reversing grid barrier (device-scope
// atomics + __threadfence; cross-XCD safe). Cooperative API abandoned (R5's
// silent launch failure).
//  - Steps 1-4 on class representatives (8^s classes).
//  - Steps 5-7: split-bf16 (hi+lo) MFMA GEMM, K=1536, XOR-swizzled LDS.
// __launch_bounds__(256,2): 2 blocks/CU guaranteed (LDS 33.8KB, VGPR<=256)
// -> all 512 blocks co-resident for the barrier.
// ---------------------------------------------------------------------------

constexpr int Bsz = 4096;
constexpr int Hsz = 512;
constexpr int G4H = 2048;
constexpr int NBLK = 512;
constexpr int NTHR = NBLK * 256;  // 131072
constexpr int NWV = NTHR / 64;    // 2048

typedef unsigned short ushort_t;
using short8 = __attribute__((ext_vector_type(8))) short;
using f32x4 = __attribute__((ext_vector_type(4))) float;

struct Prm {
  const float *emb, *w_ih, *w_hh, *b_ih, *b_hh;
  const float *wn0, *bn0, *wn1, *bn1, *wn2, *bn2, *wn3, *bn3;
  const float *wop, *bop, *gum;
  float *out;
  int *bar;  // bar[0]=count, bar[1]=sense (memset to 0 each call)
  float *E, *Eperm, *c1, *h2s, *c2s, *h3s, *c3s, *h4s, *c4s;
  float *G, *cF, *hA;
  ushort_t *AcatA, *AcatB, *Wcat;
  int *act, *cls1, *cls2, *cls3, *claim;  // claim: 8 + 64 + 512
};

__device__ __forceinline__ ushort_t f2bf_hi(float f) {
  unsigned u = __float_as_uint(f);
  u += 0x7FFF + ((u >> 16) & 1);  // RNE
  return (ushort_t)(u >> 16);
}
__device__ __forceinline__ float bf2f(ushort_t h) {
  return __uint_as_float((unsigned)h << 16);
}
__device__ __forceinline__ void glds16(const void* gsrc, void* ldst) {
  __builtin_amdgcn_global_load_lds(
      (const __attribute__((address_space(1))) void*)gsrc,
      (__attribute__((address_space(3))) void*)ldst, 16, 0, 0);
}

// sense-reversing grid barrier. All threads call. Release fence before
// arrival (L2 writeback, cross-XCD), acquire fence after (L1/L2 invalidate).
// Spin bounded so a residency failure degrades to wrong-answer, not a hang.
__device__ __forceinline__ void gbar(int* cnt, int* sense, int& ls) {
  __threadfence();   // release: this thread's writes visible device-wide
  __syncthreads();   // all threads of block fenced & arrived
  const int target = ls ^ 1;
  if (threadIdx.x == 0) {
    if (atomicAdd(cnt, 1) == NBLK - 1) {
      atomicExch(cnt, 0);
      __threadfence();
      atomicExch(sense, target);  // release flip
    } else {
      int guard = 0;
      while (atomicAdd(sense, 0) != target) {
        __builtin_amdgcn_s_sleep(2);
        if (++guard > (1 << 22)) break;  // deadlock safety valve
      }
    }
  }
  ls = target;
  __syncthreads();   // block waits on thread 0's observation
  __threadfence();   // acquire: invalidate stale cached lines
}

// full-wave dot of two 8-elem register fragments (all lanes get the sum)
__device__ __forceinline__ float dotred8(const float a[8], const float b[8]) {
  float v = a[0] * b[0] + a[1] * b[1] + a[2] * b[2] + a[3] * b[3] +
            a[4] * b[4] + a[5] * b[5] + a[6] * b[6] + a[7] * b[7];
#pragma unroll
  for (int off = 32; off > 0; off >>= 1) v += __shfl_xor(v, off, 64);
  return v;
}
__device__ __forceinline__ float dotred(const float a[8], const float* w) {
  float b[8];
#pragma unroll
  for (int u = 0; u < 8; ++u) b[u] = w[u];
  return dotred8(a, b);
}

// lane's 8 columns of the LSTM pointwise update
__device__ __forceinline__ void lstm8(const float* Eg, const float* Gg,
                                      const float* cp, int lane, float* h8,
                                      float* c8) {
  const int j0 = lane * 8;
#pragma unroll
  for (int u = 0; u < 8; ++u) {
    int j = j0 + u;
    float iv = Eg[j], fv = Eg[512 + j], gv = Eg[1024 + j], ov = Eg[1536 + j];
    if (Gg) {
      iv += Gg[j]; fv += Gg[512 + j]; gv += Gg[1024 + j]; ov += Gg[1536 + j];
    }
    float cc = cp ? cp[j] : 0.0f;
    float ig = 1.0f / (1.0f + expf(-iv));
    float fg = 1.0f / (1.0f + expf(-fv));
    float gg = tanhf(gv);
    float og = 1.0f / (1.0f + expf(-ov));
    float cn = fg * cc + ig * gg;
    c8[u] = cn;
    h8[u] = og * tanhf(cn);
  }
}

// one row's (node, op) decisions from an in-register h fragment
__device__ void decide_row(const Prm& P, const float h8[8], int lane, int r,
                           int s, int qb, int* cls_out) {
  const int i = s >> 1;
  const int K = i + 2;
  const float* wns[4] = {P.wn0, P.wn1, P.wn2, P.wn3};
  const float* bns[4] = {P.bn0, P.bn1, P.bn2, P.bn3};
  const float* wn = wns[i];
  const float* bn = bns[i];
  const float* wopi = P.wop + (size_t)i * 8 * Hsz;
  const float* bopi = P.bop + i * 8;
  const float* gn = P.gum + (size_t)(2 * s) * Bsz * 8;
  const size_t SZ = (size_t)16 * Bsz;
  float* oan = P.out + (size_t)(2 * s) * Bsz;
  float* oao = oan + Bsz;
  float* oln = P.out + SZ + (size_t)(2 * s) * Bsz;
  float* olo = oln + Bsz;
  float* oen = P.out + 2 * SZ + (size_t)(2 * s) * Bsz;
  float* oeo = oen + Bsz;

  float nl[5];
  for (int k = 0; k < K; ++k) {
    float v = dotred(h8, wn + (size_t)k * Hsz + lane * 8);
    nl[k] = 2.5f * tanhf((v + bn[k]) / 5.0f);
  }
  float ol[8];
#pragma unroll
  for (int k = 0; k < 8; ++k) {
    float v = dotred(h8, wopi + (size_t)k * Hsz + lane * 8);
    ol[k] = (v + bopi[k]) / 5.0f;
  }
  // node decision
  {
    const float* g = gn + (size_t)r * 8;
    float m = nl[0];
    for (int k = 1; k < K; ++k) m = fmaxf(m, nl[k]);
    float se = 0.0f;
    for (int k = 0; k < K; ++k) se += expf(nl[k] - m);
    float lse = logf(se);
    int a = 0;
    float best = nl[0] + g[0];
    for (int k = 1; k < K; ++k) {
      float v = nl[k] + g[k];
      if (v > best) { best = v; a = k; }
    }
    float ent = 0.0f, sel = 0.0f;
    for (int k = 0; k < K; ++k) {
      float lp = nl[k] - m - lse;
      ent -= lp * expf(lp);
      if (k == a) sel = lp;
    }
    if (lane == 0) { oan[r] = (float)a; oln[r] = sel; oen[r] = ent; }
  }
  // op decision
  {
    const float* g = gn + (size_t)Bsz * 8 + (size_t)r * 8;
    float m = ol[0];
#pragma unroll
    for (int k = 1; k < 8; ++k) m = fmaxf(m, ol[k]);
    float se = 0.0f;
#pragma unroll
    for (int k = 0; k < 8; ++k) se += expf(ol[k] - m);
    float lse = logf(se);
    int a = 0;
    float best = ol[0] + g[0];
#pragma unroll
    for (int k = 1; k < 8; ++k) {
      float v = ol[k] + g[k];
      if (v > best) { best = v; a = k; }
    }
    float ent = 0.0f, sel = 0.0f;
#pragma unroll
    for (int k = 0; k < 8; ++k) {
      float lp = ol[k] - m - lse;
      ent -= lp * expf(lp);
      if (k == a) sel = lp;
    }
    if (lane == 0) {
      oao[r] = (float)a; olo[r] = sel; oeo[r] = ent;
      P.act[r] = a;
      if (cls_out) cls_out[r] = qb + a;
    }
  }
}

// split-bf16 MFMA GEMM + fused LSTM pointwise (R4-proven body)
__device__ void gemm_phase(const Prm& P, const ushort_t* __restrict__ Acat,
                           ushort_t* __restrict__ Aout, char* smraw, int bid,
                           int tid) {
  ushort_t* sA = (ushort_t*)smraw;          // 128*64
  ushort_t* sB = sA + 128 * 64;
  float* sC = (float*)smraw;                // 64*132
  const int wave = tid >> 6, lane = tid & 63;
  const int bx = bid & 15, by = bid >> 4;
  const int r0 = by * 128, c0 = bx * 128;
  const int wr = (wave >> 1) * 64, wc = (wave & 1) * 64;
  const int mrow = lane & 15, quad = lane >> 4;
  const int slr = lane >> 3;
  const int ssw = ((lane & 7) ^ slr) << 3;

  f32x4 acc[4][4];
#pragma unroll
  for (int i = 0; i < 4; ++i)
#pragma unroll
    for (int jt = 0; jt < 4; ++jt) acc[i][jt] = (f32x4){0.f, 0.f, 0.f, 0.f};

  for (int k0 = 0; k0 < 1536; k0 += 64) {
    const int ak = (k0 < 512) ? k0 : k0 - 512;  // A dup-block remap
    __syncthreads();
#pragma unroll
    for (int q2 = 0; q2 < 8; ++q2) {
      const int g = q2 * 4 + wave;
      if (g < 16) {
        const int row = r0 + g * 8 + slr;
        glds16(Acat + (size_t)row * 1024 + ak + ssw, (char*)sA + g * 1024);
      } else {
        const int row = c0 + (g - 16) * 8 + slr;
        glds16(P.Wcat + (size_t)row * 1536 + k0 + ssw,
               (char*)sB + (g - 16) * 1024);
      }
    }
    __syncthreads();
#pragma unroll
    for (int kk = 0; kk < 2; ++kk) {
      const int swr2 = ((kk * 4 + quad) ^ (mrow & 7)) << 3;
      short8 a[4], b[4];
#pragma unroll
      for (int i = 0; i < 4; ++i)
        a[i] = *(const short8*)&sA[(wr + i * 16 + mrow) * 64 + swr2];
#pragma unroll
      for (int jt = 0; jt < 4; ++jt)
        b[jt] = *(const short8*)&sB[(wc + jt * 16 + mrow) * 64 + swr2];
#pragma unroll
      for (int i = 0; i < 4; ++i)
#pragma unroll
        for (int jt = 0; jt < 4; ++jt)
          acc[i][jt] = __builtin_amdgcn_mfma_f32_16x16x32_bf16(
              a[i], b[jt], acc[i][jt], 0, 0, 0);
    }
  }

  const int jj = tid & 31;
  const int rbase = tid >> 5;
#pragma unroll
  for (int ph = 0; ph < 2; ++ph) {
    __syncthreads();
    if ((wr >> 6) == ph) {
#pragma unroll
      for (int i = 0; i < 4; ++i)
#pragma unroll
        for (int jt = 0; jt < 4; ++jt)
#pragma unroll
          for (int rg = 0; rg < 4; ++rg)
            sC[(i * 16 + quad * 4 + rg) * 132 + wc + jt * 16 + mrow] =
                acc[i][jt][rg];
    }
    __syncthreads();
#pragma unroll
    for (int rp = 0; rp < 8; ++rp) {
      const int rl = rbase * 8 + rp;
      const int grow = r0 + ph * 64 + rl;
      float4 g4 = *(float4*)&sC[rl * 132 + jj * 4];
      const int a = P.act[grow];
      const int jglob = (c0 >> 2) + jj;
      float4 e4 = *(const float4*)&P.Eperm[(size_t)a * G4H + c0 + jj * 4];
      float iv = g4.x + e4.x, fv = g4.y + e4.y;
      float gv = g4.z + e4.z, ov = g4.w + e4.w;
      float ig = 1.0f / (1.0f + expf(-iv));
      float fg = 1.0f / (1.0f + expf(-fv));
      float gg = tanhf(gv);
      float og = 1.0f / (1.0f + expf(-ov));
      const size_t ci = (size_t)grow * Hsz + jglob;
      float cn = fg * P.cF[ci] + ig * gg;
      float hn = og * tanhf(cn);
      P.cF[ci] = cn;
      P.hA[ci] = hn;
      ushort_t hi = f2bf_hi(hn);
      Aout[(size_t)grow * 1024 + jglob] = hi;
      Aout[(size_t)grow * 1024 + 512 + jglob] = f2bf_hi(hn - bf2f(hi));
    }
  }
}

// ---------------------------------------------------------------------------
__global__ __launch_bounds__(256, 2) void mega(Prm p) {
  const int tid = threadIdx.x, bid = blockIdx.x;
  const int gtid = bid * 256 + tid;
  const int lane = tid & 63;
  const int gw = gtid >> 6;  // 0..2047
  __shared__ __align__(16) char smraw[64 * 132 * 4];  // 33792 B
  int* cnt = p.bar;
  int* sense = p.bar + 1;
  int ls = 0;

  // ---- B0: E/Eperm, Wcat, zero claims ----
  for (int idx = gtid; idx < 9 * G4H; idx += NTHR) {
    int t = idx >> 11, col = idx & 2047;
    const float* er = p.emb + (size_t)t * Hsz;
    const float* wr = p.w_ih + (size_t)col * Hsz;
    float acc = 0.0f;
    for (int k = 0; k < Hsz; k += 4) {
      float4 e = *(const float4*)(er + k);
      float4 w = *(const float4*)(wr + k);
      acc += e.x * w.x + e.y * w.y + e.z * w.z + e.w * w.w;
    }
    float v = acc + p.b_ih[col] + p.b_hh[col];
    p.E[idx] = v;
    int g = col >> 9, j = col & 511;
    p.Eperm[(size_t)t * G4H + (j << 2) + g] = v;
  }
  for (int idx = gtid; idx < 2048 * 1536; idx += NTHR) {
    int ct = idx / 1536, k = idx - ct * 1536;
    int j = ct >> 2, g = ct & 3;
    const float* sr = p.w_hh + (size_t)(g * 512 + j) * Hsz;
    ushort_t o;
    if (k < 512) {
      o = f2bf_hi(sr[k]);
    } else if (k < 1024) {
      float x = sr[k - 512];
      ushort_t hi = f2bf_hi(x);
      o = f2bf_hi(x - bf2f(hi));
    } else {
      o = f2bf_hi(sr[k - 1024]);
    }
    p.Wcat[idx] = o;
  }
  for (int idx = gtid; idx < 584; idx += NTHR) p.claim[idx] = 0;
  gbar(cnt, sense, ls);

  // ---- B1: step-0 pw (class-uniform, in registers) + decide s=0 + G1 ----
  {
    float h8[8], c8[8];
    lstm8(p.E, nullptr, nullptr, lane, h8, c8);
    if (gw == 0) {
#pragma unroll
      for (int u = 0; u < 8; ++u) p.c1[lane * 8 + u] = c8[u];
    }
    for (int r = gw; r < Bsz; r += NWV) decide_row(p, h8, lane, r, 0, 0, p.cls1);
    // G1 = h1 @ w_hh^T : 2048 outputs, one per wave, h1 straight from regs
    float v = dotred(h8, p.w_hh + (size_t)gw * Hsz + lane * 8);
    if (lane == 0) p.G[gw] = v;
  }
  gbar(cnt, sense, ls);

  // ---- B2: decide s=1 (+ claimed h2/c2 class writes) ----
  for (int r = gw; r < Bsz; r += NWV) {
    int q = p.cls1[r];
    float h8[8], c8[8];
    lstm8(p.E + (size_t)q * G4H, p.G, p.c1, lane, h8, c8);
    int old = 1;
    if (lane == 0) old = atomicExch(&p.claim[q], 1);
    old = __shfl(old, 0, 64);
    if (!old) {
#pragma unroll
      for (int u = 0; u < 8; ++u) {
        p.h2s[q * 512 + lane * 8 + u] = h8[u];
        p.c2s[q * 512 + lane * 8 + u] = c8[u];
      }
    }
    decide_row(p, h8, lane, r, 1, q * 8, p.cls2);
  }
  gbar(cnt, sense, ls);

  // ---- B3: G2 (8 x 2048) ----
  for (int o = gw; o < 8 * G4H; o += NWV) {
    int q = o >> 11, col = o & 2047;
    float h8[8];
#pragma unroll
    for (int u = 0; u < 8; ++u) h8[u] = p.h2s[q * 512 + lane * 8 + u];
    float v = dotred(h8, p.w_hh + (size_t)col * Hsz + lane * 8);
    if (lane == 0) p.G[q * G4H + col] = v;
  }
  gbar(cnt, sense, ls);

  // ---- B4: decide s=2 (+ claimed h3/c3) ----
  for (int r = gw; r < Bsz; r += NWV) {
    int q = p.cls2[r];  // 0..63
    float h8[8], c8[8];
    lstm8(p.E + (size_t)(q & 7) * G4H, p.G + (size_t)(q >> 3) * G4H,
          p.c2s + (q >> 3) * 512, lane, h8, c8);
    int old = 1;
    if (lane == 0) old = atomicExch(&p.claim[8 + q], 1);
    old = __shfl(old, 0, 64);
    if (!old) {
#pragma unroll
      for (int u = 0; u < 8; ++u) {
        p.h3s[q * 512 + lane * 8 + u] = h8[u];
        p.c3s[q * 512 + lane * 8 + u] = c8[u];
      }
    }
    decide_row(p, h8, lane, r, 2, q * 8, p.cls3);
  }
  gbar(cnt, sense, ls);

  // ---- B5: G3 (64 x 2048): wave per col, loop classes ----
  {
    float w8[8];
#pragma unroll
    for (int u = 0; u < 8; ++u) w8[u] = p.w_hh[(size_t)gw * Hsz + lane * 8 + u];
    for (int q = 0; q < 64; ++q) {
      float h8[8];
#pragma unroll
      for (int u = 0; u < 8; ++u) h8[u] = p.h3s[q * 512 + lane * 8 + u];
      float v = dotred8(h8, w8);
      if (lane == 0) p.G[q * G4H + gw] = v;
    }
  }
  gbar(cnt, sense, ls);

  // ---- B6: decide s=3 (+ claimed h4/c4) ----
  for (int r = gw; r < Bsz; r += NWV) {
    int q = p.cls3[r];  // 0..511
    float h8[8], c8[8];
    lstm8(p.E + (size_t)(q & 7) * G4H, p.G + (size_t)(q >> 3) * G4H,
          p.c3s + (q >> 3) * 512, lane, h8, c8);
    int old = 1;
    if (lane == 0) old = atomicExch(&p.claim[72 + q], 1);
    old = __shfl(old, 0, 64);
    if (!old) {
#pragma unroll
      for (int u = 0; u < 8; ++u) {
        p.h4s[q * 512 + lane * 8 + u] = h8[u];
        p.c4s[q * 512 + lane * 8 + u] = c8[u];
      }
    }
    decide_row(p, h8, lane, r, 3, 0, nullptr);
  }
  gbar(cnt, sense, ls);

  // ---- B7: G4 = h4s(512x512) @ w_hh^T, 32x64 tiles (512 tiles) ----
  {
    float* As = (float*)smraw;       // [16][36]
    float* Bs = As + 16 * 36;        // [16][68]
    const int r0 = (bid >> 5) * 32, c0 = (bid & 31) * 64;
    const int ty = tid >> 4, tx = tid & 15;
    float a00 = 0.f, a01 = 0.f, a02 = 0.f, a03 = 0.f;
    float a10 = 0.f, a11 = 0.f, a12 = 0.f, a13 = 0.f;
    for (int k0 = 0; k0 < Hsz; k0 += 16) {
      __syncthreads();
      if (tid < 128) {
        int row = tid >> 2, kc = (tid & 3) * 4;
        float4 a = *(const float4*)(p.h4s + (size_t)(r0 + row) * 512 + k0 + kc);
        As[(kc + 0) * 36 + row] = a.x;
        As[(kc + 1) * 36 + row] = a.y;
        As[(kc + 2) * 36 + row] = a.z;
        As[(kc + 3) * 36 + row] = a.w;
      }
      {
        int row = tid >> 2, kc = (tid & 3) * 4;
        float4 b = *(const float4*)(p.w_hh + (size_t)(c0 + row) * 512 + k0 + kc);
        Bs[(kc + 0) * 68 + row] = b.x;
        Bs[(kc + 1) * 68 + row] = b.y;
        Bs[(kc + 2) * 68 + row] = b.z;
        Bs[(kc + 3) * 68 + row] = b.w;
      }
      __syncthreads();
#pragma unroll
      for (int kk = 0; kk < 16; ++kk) {
        float av0 = As[kk * 36 + ty * 2], av1 = As[kk * 36 + ty * 2 + 1];
        float b0 = Bs[kk * 68 + tx * 4 + 0], b1 = Bs[kk * 68 + tx * 4 + 1];
        float b2 = Bs[kk * 68 + tx * 4 + 2], b3 = Bs[kk * 68 + tx * 4 + 3];
        a00 = fmaf(av0, b0, a00); a01 = fmaf(av0, b1, a01);
        a02 = fmaf(av0, b2, a02); a03 = fmaf(av0, b3, a03);
        a10 = fmaf(av1, b0, a10); a11 = fmaf(av1, b1, a11);
        a12 = fmaf(av1, b2, a12); a13 = fmaf(av1, b3, a13);
      }
    }
    float* Gr0 = p.G + (size_t)(r0 + ty * 2) * G4H + c0 + tx * 4;
    float* Gr1 = Gr0 + G4H;
    Gr0[0] = a00; Gr0[1] = a01; Gr0[2] = a02; Gr0[3] = a03;
    Gr1[0] = a10; Gr1[1] = a11; Gr1[2] = a12; Gr1[3] = a13;
  }
  gbar(cnt, sense, ls);

  // ---- B8: expand to rows (cF + AcatA) + decide s=4 ----
  for (int r = gw; r < Bsz; r += NWV) {
    int q = p.cls3[r];
    int t = p.act[r];
    float h8[8], c8[8];
    lstm8(p.E + (size_t)t * G4H, p.G + (size_t)q * G4H, p.c4s + q * 512, lane,
          h8, c8);
#pragma unroll
    for (int u = 0; u < 8; ++u) {
      int j = lane * 8 + u;
      p.cF[(size_t)r * 512 + j] = c8[u];
      ushort_t hi = f2bf_hi(h8[u]);
      p.AcatA[(size_t)r * 1024 + j] = hi;
      p.AcatA[(size_t)r * 1024 + 512 + j] = f2bf_hi(h8[u] - bf2f(hi));
    }
    decide_row(p, h8, lane, r, 4, 0, nullptr);
  }
  gbar(cnt, sense, ls);

  // ---- steps 5-7: MFMA GEMM phase + decide ----
  const ushort_t* ain = p.AcatA;
  ushort_t* aout = p.AcatB;
  for (int s = 5; s < 8; ++s) {
    gemm_phase(p, ain, aout, smraw, bid, tid);
    gbar(cnt, sense, ls);
    for (int r = gw; r < Bsz; r += NWV) {
      const float* hr = p.hA + (size_t)r * 512 + lane * 8;
      float4 a0 = *(const float4*)hr;
      float4 a1 = *(const float4*)(hr + 4);
      float h8[8] = {a0.x, a0.y, a0.z, a0.w, a1.x, a1.y, a1.z, a1.w};
      decide_row(p, h8, lane, r, s, 0, nullptr);
    }
    if (s < 7) gbar(cnt, sense, ls);
    const ushort_t* t2 = ain;
    ain = aout;
    aout = (ushort_t*)t2;
  }
}

// ---------------------------------------------------------------------------
extern "C" void kernel_launch(void* const* d_in, const int* in_sizes, int n_in,
                              void* d_out, int out_size, void* d_ws,
                              size_t ws_size, hipStream_t stream) {
  (void)in_sizes; (void)n_in; (void)out_size; (void)ws_size;
  Prm prm;
  prm.emb = (const float*)d_in[0];
  prm.w_ih = (const float*)d_in[1];
  prm.w_hh = (const float*)d_in[2];
  prm.b_ih = (const float*)d_in[3];
  prm.b_hh = (const float*)d_in[4];
  prm.wn0 = (const float*)d_in[5];  prm.bn0 = (const float*)d_in[6];
  prm.wn1 = (const float*)d_in[7];  prm.bn1 = (const float*)d_in[8];
  prm.wn2 = (const float*)d_in[9];  prm.bn2 = (const float*)d_in[10];
  prm.wn3 = (const float*)d_in[11]; prm.bn3 = (const float*)d_in[12];
  prm.wop = (const float*)d_in[13];
  prm.bop = (const float*)d_in[14];
  prm.gum = (const float*)d_in[15];
  prm.out = (float*)d_out;

  prm.bar = (int*)d_ws;  // first 256 B reserved for the barrier
  float* ws = (float*)((char*)d_ws + 256);
  prm.E = ws;      ws += 9 * G4H;
  prm.Eperm = ws;  ws += 9 * G4H;
  prm.c1 = ws;     ws += Hsz;
  prm.h2s = ws;    ws += 8 * Hsz;
  prm.c2s = ws;    ws += 8 * Hsz;
  prm.h3s = ws;    ws += 64 * Hsz;
  prm.c3s = ws;    ws += 64 * Hsz;
  prm.h4s = ws;    ws += 512 * Hsz;
  prm.c4s = ws;    ws += 512 * Hsz;
  prm.G = ws;      ws += 512 * G4H;
  prm.cF = ws;     ws += (size_t)Bsz * Hsz;
  prm.hA = ws;     ws += (size_t)Bsz * Hsz;
  prm.AcatA = (ushort_t*)ws; ws += (size_t)Bsz * 1024 / 2;
  prm.AcatB = (ushort_t*)ws; ws += (size_t)Bsz * 1024 / 2;
  prm.Wcat = (ushort_t*)ws;  ws += (size_t)2048 * 1536 / 2;
  prm.act = (int*)ws;
  prm.cls1 = prm.act + Bsz;
  prm.cls2 = prm.cls1 + Bsz;
  prm.cls3 = prm.cls2 + Bsz;
  prm.claim = prm.cls3 + Bsz;

  hipMemsetAsync(d_ws, 0, 256, stream);  // zero barrier state (graph-legal)
  mega<<<dim3(NBLK), dim3(256), 0, stream>>>(prm);
}

// Round 7
// 516.451 us; speedup vs baseline: 3.6178x; 3.6178x over previous
//
#include <hip/hip_runtime.h>

// ---------------------------------------------------------------------------
// NASNet controller, 13-dispatch restructure (R7).
// Key insight: class tables h_after_0..h_after_4 (1/8/64/512/4096 classes) are
// ACTION-INDEPENDENT -> compute them first (tiny GEMM chain G1..G4 fused with
// pointwise), then decides 0-4 are pure gathers fused into ONE kernel.
// Step-5 GEMM gathers A rows by class (Acat5c[q4[r]]); steps 6-7 are the
// R4-proven per-row split-bf16 MFMA GEMMs. No grid barriers anywhere.
// ---------------------------------------------------------------------------

constexpr int Bsz = 4096;
constexpr int Hsz = 512;
constexpr int G4H = 2048;
constexpr int NTHR = 512 * 256;

typedef unsigned short ushort_t;
using short8 = __attribute__((ext_vector_type(8))) short;
using f32x4 = __attribute__((ext_vector_type(4))) float;

struct DP {  // decision parameters (weights + outputs)
  const float* wn[4];
  const float* bn[4];
  const float* wop;
  const float* bop;
  const float* gum;
  float* out;
  int* act;
};

__device__ __forceinline__ ushort_t f2bf_hi(float f) {
  unsigned u = __float_as_uint(f);
  u += 0x7FFF + ((u >> 16) & 1);  // RNE
  return (ushort_t)(u >> 16);
}
__device__ __forceinline__ float bf2f(ushort_t h) {
  return __uint_as_float((unsigned)h << 16);
}
__device__ __forceinline__ void glds16(const void* gsrc, void* ldst) {
  __builtin_amdgcn_global_load_lds(
      (const __attribute__((address_space(1))) void*)gsrc,
      (__attribute__((address_space(3))) void*)ldst, 16, 0, 0);
}

// wave-dot: h8 (lane fragment) . w[lane*8..] summed over all 64 lanes
__device__ __forceinline__ float dotredw(const float h8[8], const float* w) {
  float4 w0 = *(const float4*)(w);
  float4 w1 = *(const float4*)(w + 4);
  float v = h8[0] * w0.x + h8[1] * w0.y + h8[2] * w0.z + h8[3] * w0.w +
            h8[4] * w1.x + h8[5] * w1.y + h8[6] * w1.z + h8[7] * w1.w;
#pragma unroll
  for (int off = 32; off > 0; off >>= 1) v += __shfl_xor(v, off, 64);
  return v;
}
__device__ __forceinline__ float dotred8(const float a[8], const float b[8]) {
  float v = a[0] * b[0] + a[1] * b[1] + a[2] * b[2] + a[3] * b[3] +
            a[4] * b[4] + a[5] * b[5] + a[6] * b[6] + a[7] * b[7];
#pragma unroll
  for (int off = 32; off > 0; off >>= 1) v += __shfl_xor(v, off, 64);
  return v;
}

// lane's 8 columns of the LSTM pointwise update (R6-proven)
__device__ __forceinline__ void lstm8(const float* Eg, const float* Gg,
                                      const float* cp, int lane, float* h8,
                                      float* c8) {
  const int j0 = lane * 8;
#pragma unroll
  for (int u = 0; u < 8; ++u) {
    int j = j0 + u;
    float iv = Eg[j], fv = Eg[512 + j], gv = Eg[1024 + j], ov = Eg[1536 + j];
    if (Gg) {
      iv += Gg[j]; fv += Gg[512 + j]; gv += Gg[1024 + j]; ov += Gg[1536 + j];
    }
    float cc = cp ? cp[j] : 0.0f;
    float ig = 1.0f / (1.0f + expf(-iv));
    float fg = 1.0f / (1.0f + expf(-fv));
    float gg = tanhf(gv);
    float og = 1.0f / (1.0f + expf(-ov));
    float cn = fg * cc + ig * gg;
    c8[u] = cn;
    h8[u] = og * tanhf(cn);
  }
}

// one (node, op) decision pair; returns op action (all lanes), lane0 writes
template <int K>
__device__ __forceinline__ int decide_core(const DP& P, const float h8[8],
                                           int lane, int r, int s) {
  const int i = s >> 1;
  const float* wn = P.wn[i];
  const float* bnp = P.bn[i];
  const float* wopi = P.wop + (size_t)i * (8 * Hsz);
  const float* bopi = P.bop + i * 8;
  const float* gn = P.gum + (size_t)(2 * s) * (Bsz * 8);
  const size_t SZ = (size_t)16 * Bsz;
  float* oan = P.out + (size_t)(2 * s) * Bsz;
  float* oao = oan + Bsz;
  float* oln = P.out + SZ + (size_t)(2 * s) * Bsz;
  float* olo = oln + Bsz;
  float* oen = P.out + 2 * SZ + (size_t)(2 * s) * Bsz;
  float* oeo = oen + Bsz;

  float nl[K];
#pragma unroll
  for (int k = 0; k < K; ++k) {
    float v = dotredw(h8, wn + (size_t)k * Hsz + lane * 8);
    nl[k] = 2.5f * tanhf((v + bnp[k]) / 5.0f);
  }
  float ol[8];
#pragma unroll
  for (int k = 0; k < 8; ++k) {
    float v = dotredw(h8, wopi + (size_t)k * Hsz + lane * 8);
    ol[k] = (v + bopi[k]) / 5.0f;
  }
  // node decision
  {
    const float* g = gn + (size_t)r * 8;
    float m = nl[0];
#pragma unroll
    for (int k = 1; k < K; ++k) m = fmaxf(m, nl[k]);
    float se = 0.0f;
#pragma unroll
    for (int k = 0; k < K; ++k) se += expf(nl[k] - m);
    float lse = logf(se);
    int a = 0;
    float best = nl[0] + g[0];
#pragma unroll
    for (int k = 1; k < K; ++k) {
      float v = nl[k] + g[k];
      if (v > best) { best = v; a = k; }
    }
    float ent = 0.0f, sel = 0.0f;
#pragma unroll
    for (int k = 0; k < K; ++k) {
      float lp = nl[k] - m - lse;
      ent -= lp * expf(lp);
      if (k == a) sel = lp;
    }
    if (lane == 0) { oan[r] = (float)a; oln[r] = sel; oen[r] = ent; }
  }
  // op decision
  int aop = 0;
  {
    const float* g = gn + (size_t)(Bsz * 8) + (size_t)r * 8;
    float m = ol[0];
#pragma unroll
    for (int k = 1; k < 8; ++k) m = fmaxf(m, ol[k]);
    float se = 0.0f;
#pragma unroll
    for (int k = 0; k < 8; ++k) se += expf(ol[k] - m);
    float lse = logf(se);
    float best = ol[0] + g[0];
#pragma unroll
    for (int k = 1; k < 8; ++k) {
      float v = ol[k] + g[k];
      if (v > best) { best = v; aop = k; }
    }
    float ent = 0.0f, sel = 0.0f;
#pragma unroll
    for (int k = 0; k < 8; ++k) {
      float lp = ol[k] - m - lse;
      ent -= lp * expf(lp);
      if (k == aop) sel = lp;
    }
    if (lane == 0) {
      oao[r] = (float)aop; olo[r] = sel; oeo[r] = ent; P.act[r] = aop;
    }
  }
  return aop;
}

// ---------------- K1: E/Eperm + Wcat build ---------------------------------
__global__ __launch_bounds__(256) void prep_k(
    const float* __restrict__ emb, const float* __restrict__ w_ih,
    const float* __restrict__ b_ih, const float* __restrict__ b_hh,
    const float* __restrict__ w_hh, float* __restrict__ E,
    float* __restrict__ Eperm, ushort_t* __restrict__ Wcat) {
  const int gtid = blockIdx.x * 256 + threadIdx.x;
  for (int idx = gtid; idx < 9 * G4H; idx += NTHR) {
    int t = idx >> 11, col = idx & 2047;
    const float* er = emb + (size_t)t * Hsz;
    const float* wr = w_ih + (size_t)col * Hsz;
    float acc = 0.0f;
    for (int k = 0; k < Hsz; k += 4) {
      float4 e = *(const float4*)(er + k);
      float4 w = *(const float4*)(wr + k);
      acc += e.x * w.x + e.y * w.y + e.z * w.z + e.w * w.w;
    }
    float v = acc + b_ih[col] + b_hh[col];
    E[idx] = v;
    int g = col >> 9, j = col & 511;
    Eperm[(size_t)t * G4H + (j << 2) + g] = v;
  }
  for (int idx = gtid; idx < 2048 * 1536; idx += NTHR) {
    int ct = idx / 1536, k = idx - ct * 1536;
    int j = ct >> 2, g = ct & 3;
    const float* sr = w_hh + (size_t)(g * 512 + j) * Hsz;
    ushort_t o;
    if (k < 512) {
      o = f2bf_hi(sr[k]);
    } else if (k < 1024) {
      float x = sr[k - 512];
      ushort_t hi = f2bf_hi(x);
      o = f2bf_hi(x - bf2f(hi));
    } else {
      o = f2bf_hi(sr[k - 1024]);
    }
    Wcat[idx] = o;
  }
}

// ---------------- K2: G1 + pw -> h2s/c2s (8 classes) -----------------------
__global__ __launch_bounds__(256) void g1pw_k(
    const float* __restrict__ E, const float* __restrict__ w_hh,
    float* __restrict__ h2s, float* __restrict__ c2s) {
  const int lane = threadIdx.x & 63;
  const int j = (blockIdx.x << 2) + (threadIdx.x >> 6);  // 0..511
  float h8[8], c8[8];
  lstm8(E, nullptr, nullptr, lane, h8, c8);  // h_after_0 fragment (uniform)
  // c_after_0 at col j (scalar, all lanes)
  float c0j;
  {
    float iv = E[j], gv = E[1024 + j];
    float ig = 1.0f / (1.0f + expf(-iv));
    float gg = tanhf(gv);
    float fv = E[512 + j];
    float fg = 1.0f / (1.0f + expf(-fv));
    c0j = fg * 0.0f + ig * gg;
  }
  float gi = dotredw(h8, w_hh + (size_t)j * Hsz + lane * 8);
  float gf = dotredw(h8, w_hh + (size_t)(512 + j) * Hsz + lane * 8);
  float gg_ = dotredw(h8, w_hh + (size_t)(1024 + j) * Hsz + lane * 8);
  float go = dotredw(h8, w_hh + (size_t)(1536 + j) * Hsz + lane * 8);
  if (lane < 8) {
    int t = lane;
    const float* Eg = E + (size_t)t * G4H;
    float iv = Eg[j] + gi, fv = Eg[512 + j] + gf;
    float gv = Eg[1024 + j] + gg_, ov = Eg[1536 + j] + go;
    float ig = 1.0f / (1.0f + expf(-iv));
    float fg = 1.0f / (1.0f + expf(-fv));
    float gg = tanhf(gv);
    float og = 1.0f / (1.0f + expf(-ov));
    float cn = fg * c0j + ig * gg;
    c2s[t * 512 + j] = cn;
    h2s[t * 512 + j] = og * tanhf(cn);
  }
}

// ---------------- K3: G2 + pw -> h3s/c3s (64 classes) ----------------------
__global__ __launch_bounds__(256) void g2pw_k(
    const float* __restrict__ E, const float* __restrict__ w_hh,
    const float* __restrict__ h2s, const float* __restrict__ c2s,
    float* __restrict__ h3s, float* __restrict__ c3s) {
  const int lane = threadIdx.x & 63;
  const int wid = (blockIdx.x << 2) + (threadIdx.x >> 6);  // 0..2047
  for (int task = wid; task < 8 * 512; task += 2048) {
    int q = task >> 9, j = task & 511;
    float h8[8];
    const float* hr = h2s + (size_t)q * 512 + lane * 8;
    float4 a0 = *(const float4*)hr, a1 = *(const float4*)(hr + 4);
    h8[0] = a0.x; h8[1] = a0.y; h8[2] = a0.z; h8[3] = a0.w;
    h8[4] = a1.x; h8[5] = a1.y; h8[6] = a1.z; h8[7] = a1.w;
    float gi = dotredw(h8, w_hh + (size_t)j * Hsz + lane * 8);
    float gf = dotredw(h8, w_hh + (size_t)(512 + j) * Hsz + lane * 8);
    float gg_ = dotredw(h8, w_hh + (size_t)(1024 + j) * Hsz + lane * 8);
    float go = dotredw(h8, w_hh + (size_t)(1536 + j) * Hsz + lane * 8);
    float cpj = c2s[q * 512 + j];
    if (lane < 8) {
      int t = lane;
      const float* Eg = E + (size_t)t * G4H;
      float iv = Eg[j] + gi, fv = Eg[512 + j] + gf;
      float gv = Eg[1024 + j] + gg_, ov = Eg[1536 + j] + go;
      float ig = 1.0f / (1.0f + expf(-iv));
      float fg = 1.0f / (1.0f + expf(-fv));
      float gg = tanhf(gv);
      float og = 1.0f / (1.0f + expf(-ov));
      float cn = fg * cpj + ig * gg;
      c3s[(q * 8 + t) * 512 + j] = cn;
      h3s[(q * 8 + t) * 512 + j] = og * tanhf(cn);
    }
  }
}

// ---------------- K4: G3 + pw -> h4s/c4s (512 classes), w-cached -----------
__global__ __launch_bounds__(256) void g3pw_k(
    const float* __restrict__ E, const float* __restrict__ w_hh,
    const float* __restrict__ h3s, const float* __restrict__ c3s,
    float* __restrict__ h4s, float* __restrict__ c4s) {
  const int lane = threadIdx.x & 63;
  const int gw = (blockIdx.x << 2) + (threadIdx.x >> 6);  // 0..2047
  const int j = gw >> 2, qg = gw & 3;
  float wi[8], wf[8], wg[8], wo[8];
  {
    const float* w0 = w_hh + (size_t)j * Hsz + lane * 8;
    const float* w1 = w_hh + (size_t)(512 + j) * Hsz + lane * 8;
    const float* w2 = w_hh + (size_t)(1024 + j) * Hsz + lane * 8;
    const float* w3 = w_hh + (size_t)(1536 + j) * Hsz + lane * 8;
#pragma unroll
    for (int u = 0; u < 8; ++u) {
      wi[u] = w0[u]; wf[u] = w1[u]; wg[u] = w2[u]; wo[u] = w3[u];
    }
  }
  for (int q = qg * 16; q < qg * 16 + 16; ++q) {
    float h8[8];
    const float* hr = h3s + (size_t)q * 512 + lane * 8;
    float4 a0 = *(const float4*)hr, a1 = *(const float4*)(hr + 4);
    h8[0] = a0.x; h8[1] = a0.y; h8[2] = a0.z; h8[3] = a0.w;
    h8[4] = a1.x; h8[5] = a1.y; h8[6] = a1.z; h8[7] = a1.w;
    float gi = dotred8(h8, wi);
    float gf = dotred8(h8, wf);
    float gg_ = dotred8(h8, wg);
    float go = dotred8(h8, wo);
    float cpj = c3s[q * 512 + j];
    if (lane < 8) {
      int t = lane;
      const float* Eg = E + (size_t)t * G4H;
      float iv = Eg[j] + gi, fv = Eg[512 + j] + gf;
      float gv = Eg[1024 + j] + gg_, ov = Eg[1536 + j] + go;
      float ig = 1.0f / (1.0f + expf(-iv));
      float fg = 1.0f / (1.0f + expf(-fv));
      float gg = tanhf(gv);
      float og = 1.0f / (1.0f + expf(-ov));
      float cn = fg * cpj + ig * gg;
      c4s[(q * 8 + t) * 512 + j] = cn;
      h4s[(q * 8 + t) * 512 + j] = og * tanhf(cn);
    }
  }
}

// ---------------- K5: G4 = h4s(512x512) @ w_hh^T (R4-proven gemm64) --------
__global__ __launch_bounds__(256) void gemm64(
    const float* __restrict__ A, const float* __restrict__ Bw,
    float* __restrict__ G) {
  constexpr int LDA = 68;
  __shared__ float As[16 * LDA];
  __shared__ float Bs[16 * LDA];
  const int tid = threadIdx.x;
  const int bx = blockIdx.x & 31;
  const int by = blockIdx.x >> 5;
  const int r0 = by * 64, c0 = bx * 64;
  const int tx = tid & 15, ty = tid >> 4;
  const int lr = tid >> 2;
  const int lk = (tid & 3) << 2;
  const float* Ar = A + (size_t)(r0 + lr) * Hsz;
  const float* Br = Bw + (size_t)(c0 + lr) * Hsz;
  float acc[4][4];
#pragma unroll
  for (int i = 0; i < 4; ++i)
#pragma unroll
    for (int j = 0; j < 4; ++j) acc[i][j] = 0.0f;

  for (int k0 = 0; k0 < Hsz; k0 += 16) {
    float4 a = *(const float4*)(Ar + k0 + lk);
    float4 b = *(const float4*)(Br + k0 + lk);
    __syncthreads();
    As[(lk + 0) * LDA + lr] = a.x;
    As[(lk + 1) * LDA + lr] = a.y;
    As[(lk + 2) * LDA + lr] = a.z;
    As[(lk + 3) * LDA + lr] = a.w;
    Bs[(lk + 0) * LDA + lr] = b.x;
    Bs[(lk + 1) * LDA + lr] = b.y;
    Bs[(lk + 2) * LDA + lr] = b.z;
    Bs[(lk + 3) * LDA + lr] = b.w;
    __syncthreads();
#pragma unroll
    for (int kk = 0; kk < 16; ++kk) {
      float4 av = *(const float4*)&As[kk * LDA + (ty << 2)];
      float4 bv = *(const float4*)&Bs[kk * LDA + (tx << 2)];
      float avs[4] = {av.x, av.y, av.z, av.w};
      float bvs[4] = {bv.x, bv.y, bv.z, bv.w};
#pragma unroll
      for (int i = 0; i < 4; ++i)
#pragma unroll
        for (int j = 0; j < 4; ++j) acc[i][j] = fmaf(avs[i], bvs[j], acc[i][j]);
    }
  }
#pragma unroll
  for (int i = 0; i < 4; ++i)
#pragma unroll
    for (int j = 0; j < 4; ++j)
      G[(size_t)(r0 + (ty << 2) + i) * G4H + c0 + (tx << 2) + j] = acc[i][j];
}

// ---------------- K6: h_after_4 class table (4096) + Acat5c ----------------
__global__ __launch_bounds__(256) void pw5c_k(
    const float* __restrict__ E, const float* __restrict__ G4raw,
    const float* __restrict__ c4s, float* __restrict__ h5c,
    float* __restrict__ c5c, ushort_t* __restrict__ Acat5c) {
  const int lane = threadIdx.x & 63;
  const int q4 = (blockIdx.x << 2) + (threadIdx.x >> 6);  // 0..4095
  const int q3 = q4 >> 3, t = q4 & 7;
  float h8[8], c8[8];
  lstm8(E + (size_t)t * G4H, G4raw + (size_t)q3 * G4H, c4s + (size_t)q3 * 512,
        lane, h8, c8);
#pragma unroll
  for (int u = 0; u < 8; ++u) {
    int j = lane * 8 + u;
    h5c[(size_t)q4 * 512 + j] = h8[u];
    c5c[(size_t)q4 * 512 + j] = c8[u];
    ushort_t hi = f2bf_hi(h8[u]);
    Acat5c[(size_t)q4 * 1024 + j] = hi;
    Acat5c[(size_t)q4 * 1024 + 512 + j] = f2bf_hi(h8[u] - bf2f(hi));
  }
}

// ---------------- K7: decides 0-4 fused (per-row class-chain gathers) ------
__global__ __launch_bounds__(256) void decide_early_k(
    DP P, const float* __restrict__ E, const float* __restrict__ h2s,
    const float* __restrict__ h3s, const float* __restrict__ h4s,
    const float* __restrict__ h5c, int* __restrict__ q4arr) {
  const int lane = threadIdx.x & 63;
  const int gw = (blockIdx.x << 2) + (threadIdx.x >> 6);  // 0..2047
  for (int r = gw; r < Bsz; r += 2048) {
    float h8[8], c8[8];
    lstm8(E, nullptr, nullptr, lane, h8, c8);  // h_after_0 (class-uniform)
    int tok = decide_core<2>(P, h8, lane, r, 0);
    int q = tok;
    auto loadh = [&](const float* tab, int qq) {
      const float* hr = tab + (size_t)qq * 512 + lane * 8;
      float4 a0 = *(const float4*)hr, a1 = *(const float4*)(hr + 4);
      h8[0] = a0.x; h8[1] = a0.y; h8[2] = a0.z; h8[3] = a0.w;
      h8[4] = a1.x; h8[5] = a1.y; h8[6] = a1.z; h8[7] = a1.w;
    };
    loadh(h2s, q);
    tok = decide_core<2>(P, h8, lane, r, 1);
    q = q * 8 + tok;
    loadh(h3s, q);
    tok = decide_core<3>(P, h8, lane, r, 2);
    q = q * 8 + tok;
    loadh(h4s, q);
    tok = decide_core<3>(P, h8, lane, r, 3);
    q = q * 8 + tok;  // q4
    loadh(h5c, q);
    decide_core<4>(P, h8, lane, r, 4);  // writes act[r] = tok4
    if (lane == 0) q4arr[r] = q;
  }
}

// ---------------- split-bf16 MFMA GEMM + fused LSTM pointwise --------------
// qmap != null: A row gather (Acat[qmap[row]]) and c from ctab[qmap[row]];
// qmap == null: A row = batch row, c from cF in-place.
__global__ __launch_bounds__(256) void gemm_bf16_lstm(
    const ushort_t* __restrict__ Acat, const ushort_t* __restrict__ Wcat,
    const float* __restrict__ Eperm, const int* __restrict__ act,
    const int* __restrict__ qmap, const float* __restrict__ ctab,
    float* __restrict__ cF, float* __restrict__ h_out,
    ushort_t* __restrict__ Aout) {
  __shared__ union {
    struct { ushort_t A[128 * 64]; ushort_t B[128 * 64]; } s;  // 32 KB
    float C[64 * 132];                                         // 33.8 KB
  } sm;

  const int tid = threadIdx.x;
  const int wave = tid >> 6, lane = tid & 63;
  const int bx = blockIdx.x & 15;
  const int by = blockIdx.x >> 4;
  const int r0 = by * 128, c0 = bx * 128;
  const int wr = (wave >> 1) * 64, wc = (wave & 1) * 64;
  const int mrow = lane & 15, quad = lane >> 4;
  const int slr = lane >> 3;
  const int ssw = ((lane & 7) ^ slr) << 3;

  // physical A rows this lane stages (q2 = 0..3 -> region g = q2*4+wave < 16)
  int arow[4];
#pragma unroll
  for (int q2 = 0; q2 < 4; ++q2) {
    const int lrow = r0 + (q2 * 4 + wave) * 8 + slr;
    arow[q2] = qmap ? qmap[lrow] : lrow;
  }

  f32x4 acc[4][4];
#pragma unroll
  for (int i = 0; i < 4; ++i)
#pragma unroll
    for (int jt = 0; jt < 4; ++jt) acc[i][jt] = (f32x4){0.f, 0.f, 0.f, 0.f};

  for (int k0 = 0; k0 < 1536; k0 += 64) {
    const int ak = (k0 < 512) ? k0 : k0 - 512;  // A dup-block remap
    __syncthreads();
#pragma unroll
    for (int q2 = 0; q2 < 8; ++q2) {
      const int g = q2 * 4 + wave;
      if (g < 16) {
        glds16(Acat + (size_t)arow[q2] * 1024 + ak + ssw,
               (char*)sm.s.A + g * 1024);
      } else {
        const int row = c0 + (g - 16) * 8 + slr;
        glds16(Wcat + (size_t)row * 1536 + k0 + ssw,
               (char*)sm.s.B + (g - 16) * 1024);
      }
    }
    __syncthreads();
#pragma unroll
    for (int kk = 0; kk < 2; ++kk) {
      const int swr2 = ((kk * 4 + quad) ^ (mrow & 7)) << 3;
      short8 a[4], b[4];
#pragma unroll
      for (int i = 0; i < 4; ++i)
        a[i] = *(const short8*)&sm.s.A[(wr + i * 16 + mrow) * 64 + swr2];
#pragma unroll
      for (int jt = 0; jt < 4; ++jt)
        b[jt] = *(const short8*)&sm.s.B[(wc + jt * 16 + mrow) * 64 + swr2];
#pragma unroll
      for (int i = 0; i < 4; ++i)
#pragma unroll
        for (int jt = 0; jt < 4; ++jt)
          acc[i][jt] = __builtin_amdgcn_mfma_f32_16x16x32_bf16(
              a[i], b[jt], acc[i][jt], 0, 0, 0);
    }
  }

  const int jj = tid & 31;
  const int rbase = tid >> 5;
#pragma unroll
  for (int ph = 0; ph < 2; ++ph) {
    __syncthreads();
    if ((wr >> 6) == ph) {
#pragma unroll
      for (int i = 0; i < 4; ++i)
#pragma unroll
        for (int jt = 0; jt < 4; ++jt)
#pragma unroll
          for (int rg = 0; rg < 4; ++rg)
            sm.C[(i * 16 + quad * 4 + rg) * 132 + wc + jt * 16 + mrow] =
                acc[i][jt][rg];
    }
    __syncthreads();
#pragma unroll
    for (int rp = 0; rp < 8; ++rp) {
      const int rl = rbase * 8 + rp;
      const int grow = r0 + ph * 64 + rl;
      float4 g4 = *(float4*)&sm.C[rl * 132 + jj * 4];
      const int a = act[grow];
      const int jglob = (c0 >> 2) + jj;
      float4 e4 = *(const float4*)&Eperm[(size_t)a * G4H + c0 + jj * 4];
      float iv = g4.x + e4.x, fv = g4.y + e4.y;
      float gv = g4.z + e4.z, ov = g4.w + e4.w;
      float ig = 1.0f / (1.0f + expf(-iv));
      float fg = 1.0f / (1.0f + expf(-fv));
      float gg = tanhf(gv);
      float og = 1.0f / (1.0f + expf(-ov));
      float cp;
      if (qmap) {
        cp = ctab[(size_t)qmap[grow] * Hsz + jglob];
      } else {
        cp = cF[(size_t)grow * Hsz + jglob];
      }
      float cn = fg * cp + ig * gg;
      float hn = og * tanhf(cn);
      const size_t ci = (size_t)grow * Hsz + jglob;
      cF[ci] = cn;
      h_out[ci] = hn;
      ushort_t hi = f2bf_hi(hn);
      Aout[(size_t)grow * 1024 + jglob] = hi;
      Aout[(size_t)grow * 1024 + 512 + jglob] = f2bf_hi(hn - bf2f(hi));
    }
  }
}

// ---------------- decide for steps 5-7 (per-row h from hA) -----------------
template <int K>
__global__ __launch_bounds__(256) void decide_late_k(DP P,
                                                     const float* __restrict__ hA,
                                                     int s) {
  const int lane = threadIdx.x & 63;
  const int r = (blockIdx.x << 2) + (threadIdx.x >> 6);
  const float* hr = hA + (size_t)r * Hsz + lane * 8;
  float4 a0 = *(const float4*)hr, a1 = *(const float4*)(hr + 4);
  float h8[8] = {a0.x, a0.y, a0.z, a0.w, a1.x, a1.y, a1.z, a1.w};
  decide_core<K>(P, h8, lane, r, s);
}

// ---------------------------------------------------------------------------
extern "C" void kernel_launch(void* const* d_in, const int* in_sizes, int n_in,
                              void* d_out, int out_size, void* d_ws,
                              size_t ws_size, hipStream_t stream) {
  (void)in_sizes; (void)n_in; (void)out_size; (void)ws_size;
  const float* emb = (const float*)d_in[0];
  const float* w_ih = (const float*)d_in[1];
  const float* w_hh = (const float*)d_in[2];
  const float* b_ih = (const float*)d_in[3];
  const float* b_hh = (const float*)d_in[4];

  DP P;
  P.wn[0] = (const float*)d_in[5];  P.bn[0] = (const float*)d_in[6];
  P.wn[1] = (const float*)d_in[7];  P.bn[1] = (const float*)d_in[8];
  P.wn[2] = (const float*)d_in[9];  P.bn[2] = (const float*)d_in[10];
  P.wn[3] = (const float*)d_in[11]; P.bn[3] = (const float*)d_in[12];
  P.wop = (const float*)d_in[13];
  P.bop = (const float*)d_in[14];
  P.gum = (const float*)d_in[15];
  P.out = (float*)d_out;

  float* ws = (float*)d_ws;
  float* E = ws;      ws += 9 * G4H;
  float* Eperm = ws;  ws += 9 * G4H;
  float* h2s = ws;    ws += 8 * Hsz;
  float* c2s = ws;    ws += 8 * Hsz;
  float* h3s = ws;    ws += 64 * Hsz;
  float* c3s = ws;    ws += 64 * Hsz;
  float* h4s = ws;    ws += 512 * Hsz;
  float* c4s = ws;    ws += 512 * Hsz;
  float* G4raw = ws;  ws += 512 * G4H;
  float* c5c = ws;    ws += (size_t)Bsz * Hsz;
  float* hA = ws;     ws += (size_t)Bsz * Hsz;  // h5c table, then per-row h
  float* cF = ws;     ws += (size_t)Bsz * Hsz;
  ushort_t* AcatQ = (ushort_t*)ws; ws += (size_t)Bsz * 1024 / 2;  // 5c table/pong
  ushort_t* AcatP = (ushort_t*)ws; ws += (size_t)Bsz * 1024 / 2;  // ping
  ushort_t* Wcat = (ushort_t*)ws;  ws += (size_t)2048 * 1536 / 2;
  int* act = (int*)ws;
  int* q4arr = act + Bsz;
  P.act = act;
  float* h5c = hA;  // alias: class table consumed before gemm5 writes hA

  prep_k<<<512, 256, 0, stream>>>(emb, w_ih, b_ih, b_hh, w_hh, E, Eperm, Wcat);
  g1pw_k<<<128, 256, 0, stream>>>(E, w_hh, h2s, c2s);
  g2pw_k<<<512, 256, 0, stream>>>(E, w_hh, h2s, c2s, h3s, c3s);
  g3pw_k<<<512, 256, 0, stream>>>(E, w_hh, h3s, c3s, h4s, c4s);
  gemm64<<<256, 256, 0, stream>>>(h4s, w_hh, G4raw);
  pw5c_k<<<1024, 256, 0, stream>>>(E, G4raw, c4s, h5c, c5c, AcatQ);
  decide_early_k<<<512, 256, 0, stream>>>(P, E, h2s, h3s, h4s, h5c, q4arr);
  // step 5: gather-A GEMM (rows = class q4[r]), c from c5c table
  gemm_bf16_lstm<<<512, 256, 0, stream>>>(AcatQ, Wcat, Eperm, act, q4arr, c5c,
                                          cF, hA, AcatP);
  decide_late_k<4><<<Bsz / 4, 256, 0, stream>>>(P, hA, 5);
  // step 6
  gemm_bf16_lstm<<<512, 256, 0, stream>>>(AcatP, Wcat, Eperm, act, nullptr,
                                          nullptr, cF, hA, AcatQ);
  decide_late_k<5><<<Bsz / 4, 256, 0, stream>>>(P, hA, 6);
  // step 7 (Aout -> AcatP scratch, unused)
  gemm_bf16_lstm<<<512, 256, 0, stream>>>(AcatQ, Wcat, Eperm, act, nullptr,
                                          nullptr, cF, hA, AcatP);
  decide_late_k<5><<<Bsz / 4, 256, 0, stream>>>(P, hA, 7);
}

// Round 8
// 483.596 us; speedup vs baseline: 3.8636x; 1.0679x over previous
//
#include <hip/hip_runtime.h>

// ---------------------------------------------------------------------------
// NASNet controller, R8: class-logit tables make decides 0-4 scalar.
//  - Class tables h_after_0..4 (1/8/64/512/4096 classes) are action-
//    independent -> computed first (G1..G4 chain fused with pointwise).
//  - NEW: per-class decision LOGITS (nl post-tanh, ol post-/5) precomputed:
//    L0-L3 in one kernel (585 waves), L4 fused into pw5c (h8 in registers).
//    decide_early = ONE THREAD per row: 5 gathers + tiny softmaxes.
//  - Steps 5-7: R4-proven split-bf16 MFMA GEMM (K=1536, XOR-swizzled LDS),
//    step-5 A-rows gathered by class (q4 map).
// ---------------------------------------------------------------------------

constexpr int Bsz = 4096;
constexpr int Hsz = 512;
constexpr int G4H = 2048;

typedef unsigned short ushort_t;
using short8 = __attribute__((ext_vector_type(8))) short;
using f32x4 = __attribute__((ext_vector_type(4))) float;

struct DP {  // decision parameters (weights + outputs)
  const float* wn[4];
  const float* bn[4];
  const float* wop;
  const float* bop;
  const float* gum;
  float* out;
  int* act;
};

__device__ __forceinline__ ushort_t f2bf_hi(float f) {
  unsigned u = __float_as_uint(f);
  u += 0x7FFF + ((u >> 16) & 1);  // RNE
  return (ushort_t)(u >> 16);
}
__device__ __forceinline__ float bf2f(ushort_t h) {
  return __uint_as_float((unsigned)h << 16);
}
__device__ __forceinline__ void glds16(const void* gsrc, void* ldst) {
  __builtin_amdgcn_global_load_lds(
      (const __attribute__((address_space(1))) void*)gsrc,
      (__attribute__((address_space(3))) void*)ldst, 16, 0, 0);
}

// wave-dot: h8 (lane fragment) . w[lane*8..] summed over all 64 lanes
__device__ __forceinline__ float dotredw(const float h8[8], const float* w) {
  float4 w0 = *(const float4*)(w);
  float4 w1 = *(const float4*)(w + 4);
  float v = h8[0] * w0.x + h8[1] * w0.y + h8[2] * w0.z + h8[3] * w0.w +
            h8[4] * w1.x + h8[5] * w1.y + h8[6] * w1.z + h8[7] * w1.w;
#pragma unroll
  for (int off = 32; off > 0; off >>= 1) v += __shfl_xor(v, off, 64);
  return v;
}
__device__ __forceinline__ float dotred8(const float a[8], const float b[8]) {
  float v = a[0] * b[0] + a[1] * b[1] + a[2] * b[2] + a[3] * b[3] +
            a[4] * b[4] + a[5] * b[5] + a[6] * b[6] + a[7] * b[7];
#pragma unroll
  for (int off = 32; off > 0; off >>= 1) v += __shfl_xor(v, off, 64);
  return v;
}

// lane's 8 columns of the LSTM pointwise update
__device__ __forceinline__ void lstm8(const float* Eg, const float* Gg,
                                      const float* cp, int lane, float* h8,
                                      float* c8) {
  const int j0 = lane * 8;
#pragma unroll
  for (int u = 0; u < 8; ++u) {
    int j = j0 + u;
    float iv = Eg[j], fv = Eg[512 + j], gv = Eg[1024 + j], ov = Eg[1536 + j];
    if (Gg) {
      iv += Gg[j]; fv += Gg[512 + j]; gv += Gg[1024 + j]; ov += Gg[1536 + j];
    }
    float cc = cp ? cp[j] : 0.0f;
    float ig = 1.0f / (1.0f + expf(-iv));
    float fg = 1.0f / (1.0f + expf(-fv));
    float gg = tanhf(gv);
    float og = 1.0f / (1.0f + expf(-ov));
    float cn = fg * cc + ig * gg;
    c8[u] = cn;
    h8[u] = og * tanhf(cn);
  }
}

// compute one class's logits (wave-uniform) and store 16-float record
__device__ __forceinline__ void class_logits_emit(
    const DP& P, const float h8[8], int lane, int s, float* Lt) {
  const int i = s >> 1;
  const int K = i + 2;
  const float* wn = P.wn[i];
  const float* bnp = P.bn[i];
  const float* wopi = P.wop + (size_t)i * (8 * Hsz);
  const float* bopi = P.bop + i * 8;
  for (int k = 0; k < K; ++k) {
    float v = dotredw(h8, wn + (size_t)k * Hsz + lane * 8);
    float nl = 2.5f * tanhf((v + bnp[k]) / 5.0f);
    if (lane == 0) Lt[k] = nl;
  }
#pragma unroll
  for (int k = 0; k < 8; ++k) {
    float v = dotredw(h8, wopi + (size_t)k * Hsz + lane * 8);
    if (lane == 0) Lt[8 + k] = (v + bopi[k]) / 5.0f;
  }
}

// full per-row wave decide (steps 5-7): logits computed in-kernel
template <int K>
__device__ __forceinline__ int decide_core(const DP& P, const float h8[8],
                                           int lane, int r, int s) {
  const int i = s >> 1;
  const float* wn = P.wn[i];
  const float* bnp = P.bn[i];
  const float* wopi = P.wop + (size_t)i * (8 * Hsz);
  const float* bopi = P.bop + i * 8;
  const float* gn = P.gum + (size_t)(2 * s) * (Bsz * 8);
  const size_t SZ = (size_t)16 * Bsz;
  float* oan = P.out + (size_t)(2 * s) * Bsz;
  float* oao = oan + Bsz;
  float* oln = P.out + SZ + (size_t)(2 * s) * Bsz;
  float* olo = oln + Bsz;
  float* oen = P.out + 2 * SZ + (size_t)(2 * s) * Bsz;
  float* oeo = oen + Bsz;

  float nl[K];
#pragma unroll
  for (int k = 0; k < K; ++k) {
    float v = dotredw(h8, wn + (size_t)k * Hsz + lane * 8);
    nl[k] = 2.5f * tanhf((v + bnp[k]) / 5.0f);
  }
  float ol[8];
#pragma unroll
  for (int k = 0; k < 8; ++k) {
    float v = dotredw(h8, wopi + (size_t)k * Hsz + lane * 8);
    ol[k] = (v + bopi[k]) / 5.0f;
  }
  {
    const float* g = gn + (size_t)r * 8;
    float m = nl[0];
#pragma unroll
    for (int k = 1; k < K; ++k) m = fmaxf(m, nl[k]);
    float se = 0.0f;
#pragma unroll
    for (int k = 0; k < K; ++k) se += expf(nl[k] - m);
    float lse = logf(se);
    int a = 0;
    float best = nl[0] + g[0];
#pragma unroll
    for (int k = 1; k < K; ++k) {
      float v = nl[k] + g[k];
      if (v > best) { best = v; a = k; }
    }
    float ent = 0.0f, sel = 0.0f;
#pragma unroll
    for (int k = 0; k < K; ++k) {
      float lp = nl[k] - m - lse;
      ent -= lp * expf(lp);
      if (k == a) sel = lp;
    }
    if (lane == 0) { oan[r] = (float)a; oln[r] = sel; oen[r] = ent; }
  }
  int aop = 0;
  {
    const float* g = gn + (size_t)(Bsz * 8) + (size_t)r * 8;
    float m = ol[0];
#pragma unroll
    for (int k = 1; k < 8; ++k) m = fmaxf(m, ol[k]);
    float se = 0.0f;
#pragma unroll
    for (int k = 0; k < 8; ++k) se += expf(ol[k] - m);
    float lse = logf(se);
    float best = ol[0] + g[0];
#pragma unroll
    for (int k = 1; k < 8; ++k) {
      float v = ol[k] + g[k];
      if (v > best) { best = v; aop = k; }
    }
    float ent = 0.0f, sel = 0.0f;
#pragma unroll
    for (int k = 0; k < 8; ++k) {
      float lp = ol[k] - m - lse;
      ent -= lp * expf(lp);
      if (k == aop) sel = lp;
    }
    if (lane == 0) {
      oao[r] = (float)aop; olo[r] = sel; oeo[r] = ent; P.act[r] = aop;
    }
  }
  return aop;
}

// ---------------- K1: Wcat (block-per-row) + E/Eperm -----------------------
__global__ __launch_bounds__(256) void prep_k(
    const float* __restrict__ emb, const float* __restrict__ w_ih,
    const float* __restrict__ b_ih, const float* __restrict__ b_hh,
    const float* __restrict__ w_hh, float* __restrict__ E,
    float* __restrict__ Eperm, ushort_t* __restrict__ Wcat) {
  const int bid = blockIdx.x;
  if (bid < 2048) {  // Wcat row ct = bid: [hi(512) | lo(512) | hi(512)]
    const int ct = bid;
    const int j = ct >> 2, g = ct & 3;
    const float* sr = w_hh + (size_t)(g * 512 + j) * Hsz;
    for (int k = threadIdx.x; k < 1536; k += 256) {
      ushort_t o;
      if (k < 512) {
        o = f2bf_hi(sr[k]);
      } else if (k < 1024) {
        float x = sr[k - 512];
        ushort_t hi = f2bf_hi(x);
        o = f2bf_hi(x - bf2f(hi));
      } else {
        o = f2bf_hi(sr[k - 1024]);
      }
      Wcat[(size_t)ct * 1536 + k] = o;
    }
  } else {  // E: one column per thread
    const int idx = (bid - 2048) * 256 + threadIdx.x;
    if (idx < 9 * G4H) {
      int t = idx >> 11, col = idx & 2047;
      const float* er = emb + (size_t)t * Hsz;
      const float* wr = w_ih + (size_t)col * Hsz;
      float acc = 0.0f;
      for (int k = 0; k < Hsz; k += 4) {
        float4 e = *(const float4*)(er + k);
        float4 w = *(const float4*)(wr + k);
        acc += e.x * w.x + e.y * w.y + e.z * w.z + e.w * w.w;
      }
      float v = acc + b_ih[col] + b_hh[col];
      E[idx] = v;
      int g = col >> 9, j = col & 511;
      Eperm[(size_t)t * G4H + (j << 2) + g] = v;
    }
  }
}

// ---------------- K2: G1 + pw -> h2s/c2s (8 classes) -----------------------
__global__ __launch_bounds__(256) void g1pw_k(
    const float* __restrict__ E, const float* __restrict__ w_hh,
    float* __restrict__ h2s, float* __restrict__ c2s) {
  const int lane = threadIdx.x & 63;
  const int j = (blockIdx.x << 2) + (threadIdx.x >> 6);  // 0..511
  float h8[8], c8[8];
  lstm8(E, nullptr, nullptr, lane, h8, c8);  // h_after_0 fragment (uniform)
  float c0j;
  {
    float iv = E[j], gv = E[1024 + j];
    float ig = 1.0f / (1.0f + expf(-iv));
    float gg = tanhf(gv);
    float fv = E[512 + j];
    float fg = 1.0f / (1.0f + expf(-fv));
    c0j = fg * 0.0f + ig * gg;
  }
  float gi = dotredw(h8, w_hh + (size_t)j * Hsz + lane * 8);
  float gf = dotredw(h8, w_hh + (size_t)(512 + j) * Hsz + lane * 8);
  float gg_ = dotredw(h8, w_hh + (size_t)(1024 + j) * Hsz + lane * 8);
  float go = dotredw(h8, w_hh + (size_t)(1536 + j) * Hsz + lane * 8);
  if (lane < 8) {
    int t = lane;
    const float* Eg = E + (size_t)t * G4H;
    float iv = Eg[j] + gi, fv = Eg[512 + j] + gf;
    float gv = Eg[1024 + j] + gg_, ov = Eg[1536 + j] + go;
    float ig = 1.0f / (1.0f + expf(-iv));
    float fg = 1.0f / (1.0f + expf(-fv));
    float gg = tanhf(gv);
    float og = 1.0f / (1.0f + expf(-ov));
    float cn = fg * c0j + ig * gg;
    c2s[t * 512 + j] = cn;
    h2s[t * 512 + j] = og * tanhf(cn);
  }
}

// ---------------- K3: G2 + pw -> h3s/c3s (64 classes) ----------------------
__global__ __launch_bounds__(256) void g2pw_k(
    const float* __restrict__ E, const float* __restrict__ w_hh,
    const float* __restrict__ h2s, const float* __restrict__ c2s,
    float* __restrict__ h3s, float* __restrict__ c3s) {
  const int lane = threadIdx.x & 63;
  const int wid = (blockIdx.x << 2) + (threadIdx.x >> 6);  // 0..2047
  for (int task = wid; task < 8 * 512; task += 2048) {
    int q = task >> 9, j = task & 511;
    float h8[8];
    const float* hr = h2s + (size_t)q * 512 + lane * 8;
    float4 a0 = *(const float4*)hr, a1 = *(const float4*)(hr + 4);
    h8[0] = a0.x; h8[1] = a0.y; h8[2] = a0.z; h8[3] = a0.w;
    h8[4] = a1.x; h8[5] = a1.y; h8[6] = a1.z; h8[7] = a1.w;
    float gi = dotredw(h8, w_hh + (size_t)j * Hsz + lane * 8);
    float gf = dotredw(h8, w_hh + (size_t)(512 + j) * Hsz + lane * 8);
    float gg_ = dotredw(h8, w_hh + (size_t)(1024 + j) * Hsz + lane * 8);
    float go = dotredw(h8, w_hh + (size_t)(1536 + j) * Hsz + lane * 8);
    float cpj = c2s[q * 512 + j];
    if (lane < 8) {
      int t = lane;
      const float* Eg = E + (size_t)t * G4H;
      float iv = Eg[j] + gi, fv = Eg[512 + j] + gf;
      float gv = Eg[1024 + j] + gg_, ov = Eg[1536 + j] + go;
      float ig = 1.0f / (1.0f + expf(-iv));
      float fg = 1.0f / (1.0f + expf(-fv));
      float gg = tanhf(gv);
      float og = 1.0f / (1.0f + expf(-ov));
      float cn = fg * cpj + ig * gg;
      c3s[(q * 8 + t) * 512 + j] = cn;
      h3s[(q * 8 + t) * 512 + j] = og * tanhf(cn);
    }
  }
}

// ---------------- K4: G3 + pw -> h4s/c4s (512 classes), w-cached -----------
__global__ __launch_bounds__(256) void g3pw_k(
    const float* __restrict__ E, const float* __restrict__ w_hh,
    const float* __restrict__ h3s, const float* __restrict__ c3s,
    float* __restrict__ h4s, float* __restrict__ c4s) {
  const int lane = threadIdx.x & 63;
  const int gw = (blockIdx.x << 2) + (threadIdx.x >> 6);  // 0..2047
  const int j = gw >> 2, qg = gw & 3;
  float wi[8], wf[8], wg[8], wo[8];
  {
    const float* w0 = w_hh + (size_t)j * Hsz + lane * 8;
    const float* w1 = w_hh + (size_t)(512 + j) * Hsz + lane * 8;
    const float* w2 = w_hh + (size_t)(1024 + j) * Hsz + lane * 8;
    const float* w3 = w_hh + (size_t)(1536 + j) * Hsz + lane * 8;
#pragma unroll
    for (int u = 0; u < 8; ++u) {
      wi[u] = w0[u]; wf[u] = w1[u]; wg[u] = w2[u]; wo[u] = w3[u];
    }
  }
  for (int q = qg * 16; q < qg * 16 + 16; ++q) {
    float h8[8];
    const float* hr = h3s + (size_t)q * 512 + lane * 8;
    float4 a0 = *(const float4*)hr, a1 = *(const float4*)(hr + 4);
    h8[0] = a0.x; h8[1] = a0.y; h8[2] = a0.z; h8[3] = a0.w;
    h8[4] = a1.x; h8[5] = a1.y; h8[6] = a1.z; h8[7] = a1.w;
    float gi = dotred8(h8, wi);
    float gf = dotred8(h8, wf);
    float gg_ = dotred8(h8, wg);
    float go = dotred8(h8, wo);
    float cpj = c3s[q * 512 + j];
    if (lane < 8) {
      int t = lane;
      const float* Eg = E + (size_t)t * G4H;
      float iv = Eg[j] + gi, fv = Eg[512 + j] + gf;
      float gv = Eg[1024 + j] + gg_, ov = Eg[1536 + j] + go;
      float ig = 1.0f / (1.0f + expf(-iv));
      float fg = 1.0f / (1.0f + expf(-fv));
      float gg = tanhf(gv);
      float og = 1.0f / (1.0f + expf(-ov));
      float cn = fg * cpj + ig * gg;
      c4s[(q * 8 + t) * 512 + j] = cn;
      h4s[(q * 8 + t) * 512 + j] = og * tanhf(cn);
    }
  }
}

// ---------------- K5: class logits L0-L3 (585 classes, wave each) ----------
__global__ __launch_bounds__(256) void class_logits_k(
    DP P, const float* __restrict__ E, const float* __restrict__ h2s,
    const float* __restrict__ h3s, const float* __restrict__ h4s,
    float* __restrict__ Ltab) {
  const int lane = threadIdx.x & 63;
  const int w = (blockIdx.x << 2) + (threadIdx.x >> 6);
  if (w >= 585) return;
  float h8[8];
  int s;
  if (w == 0) {
    float c8[8];
    lstm8(E, nullptr, nullptr, lane, h8, c8);
    s = 0;
  } else {
    const float* tab;
    int q;
    if (w < 9) { s = 1; q = w - 1; tab = h2s; }
    else if (w < 73) { s = 2; q = w - 9; tab = h3s; }
    else { s = 3; q = w - 73; tab = h4s; }
    const float* hr = tab + (size_t)q * 512 + lane * 8;
    float4 a0 = *(const float4*)hr, a1 = *(const float4*)(hr + 4);
    h8[0] = a0.x; h8[1] = a0.y; h8[2] = a0.z; h8[3] = a0.w;
    h8[4] = a1.x; h8[5] = a1.y; h8[6] = a1.z; h8[7] = a1.w;
  }
  class_logits_emit(P, h8, lane, s, Ltab + (size_t)w * 16);
}

// ---------------- K6: gemm64 (G4 = h4s @ w_hh^T) ---------------------------
__global__ __launch_bounds__(256) void gemm64(
    const float* __restrict__ A, const float* __restrict__ Bw,
    float* __restrict__ G) {
  constexpr int LDA = 68;
  __shared__ float As[16 * LDA];
  __shared__ float Bs[16 * LDA];
  const int tid = threadIdx.x;
  const int bx = blockIdx.x & 31;
  const int by = blockIdx.x >> 5;
  const int r0 = by * 64, c0 = bx * 64;
  const int tx = tid & 15, ty = tid >> 4;
  const int lr = tid >> 2;
  const int lk = (tid & 3) << 2;
  const float* Ar = A + (size_t)(r0 + lr) * Hsz;
  const float* Br = Bw + (size_t)(c0 + lr) * Hsz;
  float acc[4][4];
#pragma unroll
  for (int i = 0; i < 4; ++i)
#pragma unroll
    for (int j = 0; j < 4; ++j) acc[i][j] = 0.0f;

  for (int k0 = 0; k0 < Hsz; k0 += 16) {
    float4 a = *(const float4*)(Ar + k0 + lk);
    float4 b = *(const float4*)(Br + k0 + lk);
    __syncthreads();
    As[(lk + 0) * LDA + lr] = a.x;
    As[(lk + 1) * LDA + lr] = a.y;
    As[(lk + 2) * LDA + lr] = a.z;
    As[(lk + 3) * LDA + lr] = a.w;
    Bs[(lk + 0) * LDA + lr] = b.x;
    Bs[(lk + 1) * LDA + lr] = b.y;
    Bs[(lk + 2) * LDA + lr] = b.z;
    Bs[(lk + 3) * LDA + lr] = b.w;
    __syncthreads();
#pragma unroll
    for (int kk = 0; kk < 16; ++kk) {
      float4 av = *(const float4*)&As[kk * LDA + (ty << 2)];
      float4 bv = *(const float4*)&Bs[kk * LDA + (tx << 2)];
      float avs[4] = {av.x, av.y, av.z, av.w};
      float bvs[4] = {bv.x, bv.y, bv.z, bv.w};
#pragma unroll
      for (int i = 0; i < 4; ++i)
#pragma unroll
        for (int j = 0; j < 4; ++j) acc[i][j] = fmaf(avs[i], bvs[j], acc[i][j]);
    }
  }
#pragma unroll
  for (int i = 0; i < 4; ++i)
#pragma unroll
    for (int j = 0; j < 4; ++j)
      G[(size_t)(r0 + (ty << 2) + i) * G4H + c0 + (tx << 2) + j] = acc[i][j];
}

// ---------------- K7: h_after_4 table (4096) + Acat5c + L4 logits ----------
__global__ __launch_bounds__(256) void pw5c_k(
    DP P, const float* __restrict__ E, const float* __restrict__ G4raw,
    const float* __restrict__ c4s, float* __restrict__ c5c,
    ushort_t* __restrict__ Acat5c, float* __restrict__ Ltab4) {
  const int lane = threadIdx.x & 63;
  const int q4 = (blockIdx.x << 2) + (threadIdx.x >> 6);  // 0..4095
  const int q3 = q4 >> 3, t = q4 & 7;
  float h8[8], c8[8];
  lstm8(E + (size_t)t * G4H, G4raw + (size_t)q3 * G4H, c4s + (size_t)q3 * 512,
        lane, h8, c8);
#pragma unroll
  for (int u = 0; u < 8; ++u) {
    int j = lane * 8 + u;
    c5c[(size_t)q4 * 512 + j] = c8[u];
    ushort_t hi = f2bf_hi(h8[u]);
    Acat5c[(size_t)q4 * 1024 + j] = hi;
    Acat5c[(size_t)q4 * 1024 + 512 + j] = f2bf_hi(h8[u] - bf2f(hi));
  }
  class_logits_emit(P, h8, lane, 4, Ltab4 + (size_t)q4 * 16);
}

// ---------------- K8: decides 0-4, ONE THREAD per row ----------------------
__global__ __launch_bounds__(256) void decide_early_k(
    DP P, const float* __restrict__ Ltab, int* __restrict__ q4arr) {
  const int r = blockIdx.x * 256 + threadIdx.x;
  if (r >= Bsz) return;
  const size_t SZ = (size_t)16 * Bsz;
  const int Ks[5] = {2, 2, 3, 3, 4};
  const int base[5] = {0, 1, 9, 73, 585};
  int q = 0;
  int aop = 0;
#pragma unroll
  for (int s = 0; s < 5; ++s) {
    const int K = Ks[s];
    const float* Lt = Ltab + (size_t)(base[s] + q) * 16;
    const float* gn = P.gum + (size_t)(2 * s) * (Bsz * 8);
    float* oan = P.out + (size_t)(2 * s) * Bsz;
    float* oao = oan + Bsz;
    float* oln = P.out + SZ + (size_t)(2 * s) * Bsz;
    float* olo = oln + Bsz;
    float* oen = P.out + 2 * SZ + (size_t)(2 * s) * Bsz;
    float* oeo = oen + Bsz;
    // node decision
    {
      float nl[5];
      for (int k = 0; k < K; ++k) nl[k] = Lt[k];
      const float* g = gn + (size_t)r * 8;
      float m = nl[0];
      for (int k = 1; k < K; ++k) m = fmaxf(m, nl[k]);
      float se = 0.0f;
      for (int k = 0; k < K; ++k) se += expf(nl[k] - m);
      float lse = logf(se);
      int a = 0;
      float best = nl[0] + g[0];
      for (int k = 1; k < K; ++k) {
        float v = nl[k] + g[k];
        if (v > best) { best = v; a = k; }
      }
      float ent = 0.0f, sel = 0.0f;
      for (int k = 0; k < K; ++k) {
        float lp = nl[k] - m - lse;
        ent -= lp * expf(lp);
        if (k == a) sel = lp;
      }
      oan[r] = (float)a; oln[r] = sel; oen[r] = ent;
    }
    // op decision
    {
      float ol[8];
#pragma unroll
      for (int k = 0; k < 8; ++k) ol[k] = Lt[8 + k];
      const float* g = gn + (size_t)(Bsz * 8) + (size_t)r * 8;
      float m = ol[0];
#pragma unroll
      for (int k = 1; k < 8; ++k) m = fmaxf(m, ol[k]);
      float se = 0.0f;
#pragma unroll
      for (int k = 0; k < 8; ++k) se += expf(ol[k] - m);
      float lse = logf(se);
      aop = 0;
      float best = ol[0] + g[0];
#pragma unroll
      for (int k = 1; k < 8; ++k) {
        float v = ol[k] + g[k];
        if (v > best) { best = v; aop = k; }
      }
      float ent = 0.0f, sel = 0.0f;
#pragma unroll
      for (int k = 0; k < 8; ++k) {
        float lp = ol[k] - m - lse;
        ent -= lp * expf(lp);
        if (k == aop) sel = lp;
      }
      oao[r] = (float)aop; olo[r] = sel; oeo[r] = ent;
    }
    if (s < 4) q = q * 8 + aop;  // class chain; s=4's q stays = q4
  }
  q4arr[r] = q;
  P.act[r] = aop;
}

// ---------------- split-bf16 MFMA GEMM + fused LSTM pointwise --------------
__global__ __launch_bounds__(256) void gemm_bf16_lstm(
    const ushort_t* __restrict__ Acat, const ushort_t* __restrict__ Wcat,
    const float* __restrict__ Eperm, const int* __restrict__ act,
    const int* __restrict__ qmap, const float* __restrict__ ctab,
    float* __restrict__ cF, float* __restrict__ h_out,
    ushort_t* __restrict__ Aout) {
  __shared__ union {
    struct { ushort_t A[128 * 64]; ushort_t B[128 * 64]; } s;  // 32 KB
    float C[64 * 132];                                         // 33.8 KB
  } sm;

  const int tid = threadIdx.x;
  const int wave = tid >> 6, lane = tid & 63;
  const int bx = blockIdx.x & 15;
  const int by = blockIdx.x >> 4;
  const int r0 = by * 128, c0 = bx * 128;
  const int wr = (wave >> 1) * 64, wc = (wave & 1) * 64;
  const int mrow = lane & 15, quad = lane >> 4;
  const int slr = lane >> 3;
  const int ssw = ((lane & 7) ^ slr) << 3;

  int arow[4];
#pragma unroll
  for (int q2 = 0; q2 < 4; ++q2) {
    const int lrow = r0 + (q2 * 4 + wave) * 8 + slr;
    arow[q2] = qmap ? qmap[lrow] : lrow;
  }

  f32x4 acc[4][4];
#pragma unroll
  for (int i = 0; i < 4; ++i)
#pragma unroll
    for (int jt = 0; jt < 4; ++jt) acc[i][jt] = (f32x4){0.f, 0.f, 0.f, 0.f};

  for (int k0 = 0; k0 < 1536; k0 += 64) {
    const int ak = (k0 < 512) ? k0 : k0 - 512;  // A dup-block remap
    __syncthreads();
#pragma unroll
    for (int q2 = 0; q2 < 8; ++q2) {
      const int g = q2 * 4 + wave;
      if (g < 16) {
        glds16(Acat + (size_t)arow[q2] * 1024 + ak + ssw,
               (char*)sm.s.A + g * 1024);
      } else {
        const int row = c0 + (g - 16) * 8 + slr;
        glds16(Wcat + (size_t)row * 1536 + k0 + ssw,
               (char*)sm.s.B + (g - 16) * 1024);
      }
    }
    __syncthreads();
#pragma unroll
    for (int kk = 0; kk < 2; ++kk) {
      const int swr2 = ((kk * 4 + quad) ^ (mrow & 7)) << 3;
      short8 a[4], b[4];
#pragma unroll
      for (int i = 0; i < 4; ++i)
        a[i] = *(const short8*)&sm.s.A[(wr + i * 16 + mrow) * 64 + swr2];
#pragma unroll
      for (int jt = 0; jt < 4; ++jt)
        b[jt] = *(const short8*)&sm.s.B[(wc + jt * 16 + mrow) * 64 + swr2];
#pragma unroll
      for (int i = 0; i < 4; ++i)
#pragma unroll
        for (int jt = 0; jt < 4; ++jt)
          acc[i][jt] = __builtin_amdgcn_mfma_f32_16x16x32_bf16(
              a[i], b[jt], acc[i][jt], 0, 0, 0);
    }
  }

  const int jj = tid & 31;
  const int rbase = tid >> 5;
#pragma unroll
  for (int ph = 0; ph < 2; ++ph) {
    __syncthreads();
    if ((wr >> 6) == ph) {
#pragma unroll
      for (int i = 0; i < 4; ++i)
#pragma unroll
        for (int jt = 0; jt < 4; ++jt)
#pragma unroll
          for (int rg = 0; rg < 4; ++rg)
            sm.C[(i * 16 + quad * 4 + rg) * 132 + wc + jt * 16 + mrow] =
                acc[i][jt][rg];
    }
    __syncthreads();
#pragma unroll
    for (int rp = 0; rp < 8; ++rp) {
      const int rl = rbase * 8 + rp;
      const int grow = r0 + ph * 64 + rl;
      float4 g4 = *(float4*)&sm.C[rl * 132 + jj * 4];
      const int a = act[grow];
      const int jglob = (c0 >> 2) + jj;
      float4 e4 = *(const float4*)&Eperm[(size_t)a * G4H + c0 + jj * 4];
      float iv = g4.x + e4.x, fv = g4.y + e4.y;
      float gv = g4.z + e4.z, ov = g4.w + e4.w;
      float ig = 1.0f / (1.0f + expf(-iv));
      float fg = 1.0f / (1.0f + expf(-fv));
      float gg = tanhf(gv);
      float og = 1.0f / (1.0f + expf(-ov));
      float cp;
      if (qmap) {
        cp = ctab[(size_t)qmap[grow] * Hsz + jglob];
      } else {
        cp = cF[(size_t)grow * Hsz + jglob];
      }
      float cn = fg * cp + ig * gg;
      float hn = og * tanhf(cn);
      const size_t ci = (size_t)grow * Hsz + jglob;
      cF[ci] = cn;
      h_out[ci] = hn;
      ushort_t hi = f2bf_hi(hn);
      Aout[(size_t)grow * 1024 + jglob] = hi;
      Aout[(size_t)grow * 1024 + 512 + jglob] = f2bf_hi(hn - bf2f(hi));
    }
  }
}

// ---------------- decide for steps 5-7 (per-row h from hA) -----------------
template <int K>
__global__ __launch_bounds__(256) void decide_late_k(DP P,
                                                     const float* __restrict__ hA,
                                                     int s) {
  const int lane = threadIdx.x & 63;
  const int r = (blockIdx.x << 2) + (threadIdx.x >> 6);
  const float* hr = hA + (size_t)r * Hsz + lane * 8;
  float4 a0 = *(const float4*)hr, a1 = *(const float4*)(hr + 4);
  float h8[8] = {a0.x, a0.y, a0.z, a0.w, a1.x, a1.y, a1.z, a1.w};
  decide_core<K>(P, h8, lane, r, s);
}

// ---------------------------------------------------------------------------
extern "C" void kernel_launch(void* const* d_in, const int* in_sizes, int n_in,
                              void* d_out, int out_size, void* d_ws,
                              size_t ws_size, hipStream_t stream) {
  (void)in_sizes; (void)n_in; (void)out_size; (void)ws_size;
  const float* emb = (const float*)d_in[0];
  const float* w_ih = (const float*)d_in[1];
  const float* w_hh = (const float*)d_in[2];
  const float* b_ih = (const float*)d_in[3];
  const float* b_hh = (const float*)d_in[4];

  DP P;
  P.wn[0] = (const float*)d_in[5];  P.bn[0] = (const float*)d_in[6];
  P.wn[1] = (const float*)d_in[7];  P.bn[1] = (const float*)d_in[8];
  P.wn[2] = (const float*)d_in[9];  P.bn[2] = (const float*)d_in[10];
  P.wn[3] = (const float*)d_in[11]; P.bn[3] = (const float*)d_in[12];
  P.wop = (const float*)d_in[13];
  P.bop = (const float*)d_in[14];
  P.gum = (const float*)d_in[15];
  P.out = (float*)d_out;

  float* ws = (float*)d_ws;
  float* E = ws;      ws += 9 * G4H;
  float* Eperm = ws;  ws += 9 * G4H;
  float* h2s = ws;    ws += 8 * Hsz;
  float* c2s = ws;    ws += 8 * Hsz;
  float* h3s = ws;    ws += 64 * Hsz;
  float* c3s = ws;    ws += 64 * Hsz;
  float* h4s = ws;    ws += 512 * Hsz;
  float* c4s = ws;    ws += 512 * Hsz;
  float* G4raw = ws;  ws += 512 * G4H;
  float* c5c = ws;    ws += (size_t)Bsz * Hsz;
  float* hA = ws;     ws += (size_t)Bsz * Hsz;
  float* cF = ws;     ws += (size_t)Bsz * Hsz;
  float* Ltab = ws;   ws += (size_t)(585 + 4096) * 16;
  ushort_t* AcatQ = (ushort_t*)ws; ws += (size_t)Bsz * 1024 / 2;
  ushort_t* AcatP = (ushort_t*)ws; ws += (size_t)Bsz * 1024 / 2;
  ushort_t* Wcat = (ushort_t*)ws;  ws += (size_t)2048 * 1536 / 2;
  int* act = (int*)ws;
  int* q4arr = act + Bsz;
  P.act = act;
  float* Ltab4 = Ltab + (size_t)585 * 16;

  prep_k<<<2120, 256, 0, stream>>>(emb, w_ih, b_ih, b_hh, w_hh, E, Eperm, Wcat);
  g1pw_k<<<128, 256, 0, stream>>>(E, w_hh, h2s, c2s);
  g2pw_k<<<512, 256, 0, stream>>>(E, w_hh, h2s, c2s, h3s, c3s);
  g3pw_k<<<512, 256, 0, stream>>>(E, w_hh, h3s, c3s, h4s, c4s);
  class_logits_k<<<147, 256, 0, stream>>>(P, E, h2s, h3s, h4s, Ltab);
  gemm64<<<256, 256, 0, stream>>>(h4s, w_hh, G4raw);
  pw5c_k<<<1024, 256, 0, stream>>>(P, E, G4raw, c4s, c5c, AcatQ, Ltab4);
  decide_early_k<<<16, 256, 0, stream>>>(P, Ltab, q4arr);
  // step 5: gather-A GEMM (rows = class q4[r]), c from c5c table
  gemm_bf16_lstm<<<512, 256, 0, stream>>>(AcatQ, Wcat, Eperm, act, q4arr, c5c,
                                          cF, hA, AcatP);
  decide_late_k<4><<<Bsz / 4, 256, 0, stream>>>(P, hA, 5);
  // step 6
  gemm_bf16_lstm<<<512, 256, 0, stream>>>(AcatP, Wcat, Eperm, act, nullptr,
                                          nullptr, cF, hA, AcatQ);
  decide_late_k<5><<<Bsz / 4, 256, 0, stream>>>(P, hA, 6);
  // step 7 (Aout -> AcatP scratch, unused)
  gemm_bf16_lstm<<<512, 256, 0, stream>>>(AcatQ, Wcat, Eperm, act, nullptr,
                                          nullptr, cF, hA, AcatP);
  decide_late_k<5><<<Bsz / 4, 256, 0, stream>>>(P, hA, 7);
}